// Round 4
// baseline (501.550 us; speedup 1.0000x reference)
//
#include <hip/hip_runtime.h>

// ZeroWeave: x[B,C,64,64] -> out[B,C,190,190], out[:,:,::3,::3]=x, rest 0.
// B=32, C=64, s=3. out = 295.7 MB, x = 33.5 MB -> memory floor ~52 us @6.3 TB/s.
//
// R8 = CALIBRATION ROUND. Four disjoint write paths (R3 branchy, R4 LDS-table
// linear, R5 register-compose strided, R7 nontemporal) all land at the same
// ~140-155 us *residual* (dur_us - fill), and that residual tracks the
// machine-speed variance of the fills, not our kernel changes. Hypotheses:
//   H1: kernel really ~140 us (2.3 TB/s, unexplained backpressure)
//   H2: kernel ~50-70 us (at memory floor since R4); residual = fill
//       + ~80-100 us of tiny memset/restore dispatch launch overhead
//       that kernel changes cannot touch.
// Instrument: launch the IDENTICAL kernel 3x (idempotent, graph-safe).
// dur_us delta vs R7 (342) = 2 x t_kernel.
//   H2 -> ~440-480 total -> kernel at floor -> restore 1x, declare roofline.
//   H1 -> ~600-660 total -> backpressure real -> attack write path.
//
// Kernel body identical to R7 (register-compose + nontemporal stores).

typedef float f32x4 __attribute__((ext_vector_type(4)));
typedef float f32x2 __attribute__((ext_vector_type(2)));

constexpr int NPLANES    = 32 * 64;   // 2048
constexpr int BLOCK      = 192;       // 3 waves: 2x96 data slots, 189 zero slots
constexpr int PLANE_IN_F = 64 * 64;   // 4096 floats
constexpr int PLANE_OUT4 = 9025;      // 190*190/4 float4
constexpr int GROUPS     = 31;        // full 6-row groups (rows 0..185)

__global__ __launch_bounds__(BLOCK) void ZeroWeave_89601607729830_kernel(
    const float* __restrict__ x, float* __restrict__ out) {
    const int bc = blockIdx.x;
    const int t  = threadIdx.x;

    const float* xp = x + (size_t)bc * PLANE_IN_F;
    f32x4* op = reinterpret_cast<f32x4*>(out) + (size_t)bc * PLANE_OUT4;

    // ---- data phase: 192 threads cover 2 groups/iter, 16 iters (g = 2k+hi).
    {
        const int hi   = (t >= 96) ? 1 : 0;   // which of the 2 groups
        const int r    = t - 96 * hi;         // data slot in pattern, 0..95
        const int half = (r >= 48) ? 1 : 0;   // 0: pattern row 0, 1: pattern row 3
        const int rr   = r - 48 * half;       // 0..47
        const unsigned c = (unsigned)rr / 3u;         // x float4-chunk, 0..15
        const unsigned m = (unsigned)rr - 3u * c;
        unsigned cls = m + (unsigned)half;
        if (cls >= 3u) cls -= 3u;
        const int sel2 = half ? (m == 2u) : (m != 0u);
        const int xoff = half * 64 + 4 * (int)c + 2 * sel2; // float offset in x row-pair
        const int qofs = r + (half ? 94 : 0);               // slot within group
        const bool p0 = (cls == 0u), p1 = (cls == 1u), p2 = (cls == 2u);

        const float* xa = xp + xoff;   // + g*128 per group
        f32x4* oa = op + qofs;         // + g*285 per group
#pragma unroll 4
        for (int k = 0; k < 16; ++k) {
            const int g = 2 * k + hi;
            const f32x2 v = __builtin_nontemporal_load(
                reinterpret_cast<const f32x2*>(xa + g * 128));
            f32x4 o;
            o.x = p0 ? v.x : 0.0f;
            o.y = p2 ? v.y : 0.0f;
            o.z = p1 ? v.x : 0.0f;
            o.w = p0 ? v.y : 0.0f;
            __builtin_nontemporal_store(o, &oa[g * 285]);
        }
    }

    // ---- zero phase: thread t owns one fixed zero-slot position.
    {
        const f32x4 z = {0.0f, 0.0f, 0.0f, 0.0f};
        if (t < 189) {
            const int myq = 48 + t + ((t >= 94) ? 48 : 0); // 48..141, 190..284
            f32x4* o = op + myq;
#pragma unroll
            for (int g = 0; g < GROUPS; ++g)
                __builtin_nontemporal_store(z, &o[g * 285]);
            if (t < 94)                 // partial group (g=31): only 48..141
                __builtin_nontemporal_store(z, &o[GROUPS * 285]);
        }
    }
}

extern "C" void kernel_launch(void* const* d_in, const int* in_sizes, int n_in,
                              void* d_out, int out_size, void* d_ws, size_t ws_size,
                              hipStream_t stream) {
    const float* x = (const float*)d_in[0];
    // d_in[1] is num_zeros (==2), baked into constants.
    float* out = (float*)d_out;

    // CALIBRATION: 3 identical launches. Kernel is idempotent, so the result
    // is unchanged; dur_us delta vs single-launch R7 = 2 x true kernel time.
    ZeroWeave_89601607729830_kernel<<<NPLANES, BLOCK, 0, stream>>>(x, out);
    ZeroWeave_89601607729830_kernel<<<NPLANES, BLOCK, 0, stream>>>(x, out);
    ZeroWeave_89601607729830_kernel<<<NPLANES, BLOCK, 0, stream>>>(x, out);
}

// Round 5
// 500.230 us; speedup vs baseline: 1.0026x; 1.0026x over previous
//
#include <hip/hip_runtime.h>

// ZeroWeave: x[B,C,64,64] -> out[B,C,190,190], out[:,:,::3,::3]=x, rest 0.
// B=32, C=64, s=3. out = 295.7 MB, x = 33.5 MB -> memory floor ~52 us @6.3 TB/s.
//
// R8 calibration (3x identical launches): t_kernel = (501.6-342.2)/2 = 79.7 us
// = 4.1 TB/s mixed stream vs fill's 6.37 TB/s store-only. Harness overhead
// (fills + tiny restore dispatches) ~260 us of dur_us is untouchable.
//
// R9 theory: remaining structural difference vs the fill is the DOUBLE SWEEP:
// data phase visits every 4560B group writing only 2x768B runs, then the zero
// phase re-sweeps all groups writing the complementary runs. Every DRAM row /
// L2 sector is touched twice; run-boundary lines are written at two separated
// times. R9 = single sweep: thread q<285 owns pattern slot q (data/zero class
// loop-invariant), g-loop writes one contiguous 4560B group per iteration in
// monotone address order; each 128B line written once, by one wave. Zero
// threads take the same branchless cndmask path (dummy L1-hit load).
//
// Pattern group (6 out rows = 285 float4): [0..47 data][48..141 zero]
// [142..189 data][190..284 zero]. Partial group g=31 = pattern slots 0..189.
// Verified data mapping (half: 0=pattern row 0, 1=row 3; x row = 2g+half):
//   c = rr/3, m = rr%3, cls = (m+half)%3, sel2 = half ? m==2 : m!=0,
//   xoff = half*64 + 4c + 2*sel2; compose {p0?vx, p2?vy, p1?vx, p0?vy}.
//
// STILL 3x-LAUNCH CALIBRATION: dur_us delta vs R8 (501.6) = 3 x kernel delta.
// Restore single launch next round.

typedef float f32x4 __attribute__((ext_vector_type(4)));
typedef float f32x2 __attribute__((ext_vector_type(2)));

constexpr int NPLANES    = 32 * 64;   // 2048
constexpr int BLOCK      = 320;       // 5 waves; threads 0..284 own one slot
constexpr int PLANE_IN_F = 64 * 64;   // 4096 floats
constexpr int PLANE_OUT4 = 9025;      // 190*190/4 float4
constexpr int GROUP4     = 285;       // float4 per 6-row group
constexpr int GROUPS     = 31;        // full groups (rows 0..185)

__global__ __launch_bounds__(BLOCK) void ZeroWeave_89601607729830_kernel(
    const float* __restrict__ x, float* __restrict__ out) {
    const int bc = blockIdx.x;
    const int q  = threadIdx.x;
    if (q >= GROUP4) return;          // threads 285..319 idle (tail of wave 4)

    const float* xp = x + (size_t)bc * PLANE_IN_F;
    f32x4* op = reinterpret_cast<f32x4*>(out) + (size_t)bc * PLANE_OUT4;

    // ---- loop-invariant slot classification (pattern slot q).
    int  half   = 0;
    int  rr     = 0;
    bool isData = false;
    if (q < 48)                    { isData = true; half = 0; rr = q; }
    else if (q >= 142 && q < 190)  { isData = true; half = 1; rr = q - 142; }
    const unsigned c = (unsigned)rr / 3u;
    const unsigned m = (unsigned)rr - 3u * c;
    unsigned cls = m + (unsigned)half;
    if (cls >= 3u) cls -= 3u;
    const int  sel2 = half ? (m == 2u) : (m != 0u);
    const int  xoff = isData ? (half * 64 + 4 * (int)c + 2 * sel2) : 0;
    const bool p0 = isData && (cls == 0u);
    const bool p1 = isData && (cls == 1u);
    const bool p2 = isData && (cls == 2u);

    const float* xa = xp + xoff;   // + g*128 per group (zero threads: L1 hit)
    f32x4* oa = op + q;            // + g*285 per group

    // ---- single sweep: one contiguous 4560B group per iteration, in order.
#pragma unroll 4
    for (int g = 0; g < GROUPS; ++g) {
        const f32x2 v = __builtin_nontemporal_load(
            reinterpret_cast<const f32x2*>(xa + g * 128));
        f32x4 o;
        o.x = p0 ? v.x : 0.0f;
        o.y = p2 ? v.y : 0.0f;
        o.z = p1 ? v.x : 0.0f;
        o.w = p0 ? v.y : 0.0f;
        __builtin_nontemporal_store(o, &oa[g * GROUP4]);
    }
    // ---- partial group g=31: rows 186..189 = pattern slots 0..189.
    if (q < 190) {
        const f32x2 v = __builtin_nontemporal_load(
            reinterpret_cast<const f32x2*>(xa + GROUPS * 128));
        f32x4 o;
        o.x = p0 ? v.x : 0.0f;
        o.y = p2 ? v.y : 0.0f;
        o.z = p1 ? v.x : 0.0f;
        o.w = p0 ? v.y : 0.0f;
        __builtin_nontemporal_store(o, &oa[GROUPS * GROUP4]);
    }
}

extern "C" void kernel_launch(void* const* d_in, const int* in_sizes, int n_in,
                              void* d_out, int out_size, void* d_ws, size_t ws_size,
                              hipStream_t stream) {
    const float* x = (const float*)d_in[0];
    // d_in[1] is num_zeros (==2), baked into constants.
    float* out = (float*)d_out;

    // CALIBRATION: 3 identical launches (idempotent). Delta vs R8 = 3x the
    // per-kernel delta. Restore single launch once the A/B is read out.
    ZeroWeave_89601607729830_kernel<<<NPLANES, BLOCK, 0, stream>>>(x, out);
    ZeroWeave_89601607729830_kernel<<<NPLANES, BLOCK, 0, stream>>>(x, out);
    ZeroWeave_89601607729830_kernel<<<NPLANES, BLOCK, 0, stream>>>(x, out);
}

// Round 6
// 470.757 us; speedup vs baseline: 1.0654x; 1.0626x over previous
//
#include <hip/hip_runtime.h>

// ZeroWeave: x[B,C,64,64] -> out[B,C,190,190], out[:,:,::3,::3]=x, rest 0.
// B=32, C=64, s=3. out = 295.7 MB, x = 33.5 MB -> memory floor ~52 us @6.3 TB/s.
//
// Calibrated ledger (3x-launch): R7/R9 global-NT-load+store structure =
// 79.7 us (4.1 TB/s) regardless of sweep order / NT / instruction count.
// Fill = 6.37 TB/s PURE-STORE stream. Surviving theory: continuous
// read/write mixing (8B global read per iteration interleaved into the
// store stream; NT loads may bypass caches -> repeated DRAM reads) costs
// HBM bus-turnaround. R4 (LDS-staged x, store-pure steady state) was never
// calibrated and its cross-run residual suggests ~60 us.
//
// R10 = calibrated A/B of store-pure: stage x plane (16 KB) into LDS once
// (coalesced float4 burst, reads concentrated at kernel start), hot loop =
// LDS float2 read + compose + PLAIN linear store (matches fill exactly;
// NT-vs-plain already proven neutral). Slot-ownership single sweep kept.
// STILL 3x-LAUNCH: dur_us delta vs R9 (500.2) = 3 x kernel delta.
//   mixing theory right -> ~440-465; neutral -> ~495-505 -> declare ceiling.
//
// Pattern group (6 out rows = 285 float4): [0..47 data][48..141 zero]
// [142..189 data][190..284 zero]. Partial group g=31 = pattern slots 0..189.
// Verified data mapping (half: 0=pattern row 0, 1=row 3; x row = 2g+half):
//   c = rr/3, m = rr%3, cls = (m+half)%3, sel2 = half ? m==2 : m!=0,
//   xoff = half*64 + 4c + 2*sel2; compose {p0?vx, p2?vy, p1?vx, p0?vy}.

typedef float f32x4 __attribute__((ext_vector_type(4)));
typedef float f32x2 __attribute__((ext_vector_type(2)));

constexpr int NPLANES    = 32 * 64;   // 2048
constexpr int BLOCK      = 320;       // 5 waves; threads 0..284 own one slot
constexpr int PLANE_IN_F = 64 * 64;   // 4096 floats = 16 KB
constexpr int PLANE_OUT4 = 9025;      // 190*190/4 float4
constexpr int GROUP4     = 285;       // float4 per 6-row group
constexpr int GROUPS     = 31;        // full groups (rows 0..185)

__global__ __launch_bounds__(BLOCK) void ZeroWeave_89601607729830_kernel(
    const float* __restrict__ x, float* __restrict__ out) {
    __shared__ float xs[PLANE_IN_F];

    const int bc = blockIdx.x;
    const int t  = threadIdx.x;

    // ---- stage x plane -> LDS (coalesced float4; all reads up-front).
    {
        const f32x4* xp4 = reinterpret_cast<const f32x4*>(x + (size_t)bc * PLANE_IN_F);
        f32x4* xl = reinterpret_cast<f32x4*>(xs);
#pragma unroll
        for (int k = 0; k < 4; ++k) {
            const int i = k * BLOCK + t;
            if (i < PLANE_IN_F / 4) xl[i] = xp4[i];
        }
    }
    __syncthreads();
    if (t >= GROUP4) return;          // after the barrier!

    f32x4* op = reinterpret_cast<f32x4*>(out) + (size_t)bc * PLANE_OUT4;

    // ---- loop-invariant slot classification (pattern slot t).
    int  half   = 0;
    int  rr     = 0;
    bool isData = false;
    if (t < 48)                    { isData = true; half = 0; rr = t; }
    else if (t >= 142 && t < 190)  { isData = true; half = 1; rr = t - 142; }
    const unsigned c = (unsigned)rr / 3u;
    const unsigned m = (unsigned)rr - 3u * c;
    unsigned cls = m + (unsigned)half;
    if (cls >= 3u) cls -= 3u;
    const int  sel2 = half ? (m == 2u) : (m != 0u);
    const int  xoff = isData ? (half * 64 + 4 * (int)c + 2 * sel2) : 0;
    const bool p0 = isData && (cls == 0u);
    const bool p1 = isData && (cls == 1u);
    const bool p2 = isData && (cls == 2u);

    const float* xa = xs + xoff;   // + g*128 per group (zero threads: bank-0 bcast)
    f32x4* oa = op + t;            // + g*285 per group

    // ---- single sweep: one contiguous 4560B group per iteration, in order.
    // Hot loop global traffic = stores ONLY (pure store stream, like the fill).
#pragma unroll 4
    for (int g = 0; g < GROUPS; ++g) {
        const f32x2 v = *reinterpret_cast<const f32x2*>(xa + g * 128);
        f32x4 o;
        o.x = p0 ? v.x : 0.0f;
        o.y = p2 ? v.y : 0.0f;
        o.z = p1 ? v.x : 0.0f;
        o.w = p0 ? v.y : 0.0f;
        oa[g * GROUP4] = o;
    }
    // ---- partial group g=31: rows 186..189 = pattern slots 0..189.
    if (t < 190) {
        const f32x2 v = *reinterpret_cast<const f32x2*>(xa + GROUPS * 128);
        f32x4 o;
        o.x = p0 ? v.x : 0.0f;
        o.y = p2 ? v.y : 0.0f;
        o.z = p1 ? v.x : 0.0f;
        o.w = p0 ? v.y : 0.0f;
        oa[GROUPS * GROUP4] = o;
    }
}

extern "C" void kernel_launch(void* const* d_in, const int* in_sizes, int n_in,
                              void* d_out, int out_size, void* d_ws, size_t ws_size,
                              hipStream_t stream) {
    const float* x = (const float*)d_in[0];
    // d_in[1] is num_zeros (==2), baked into constants.
    float* out = (float*)d_out;

    // CALIBRATION: 3 identical launches (idempotent). Delta vs R9 = 3x the
    // per-kernel delta. Restore single launch once the A/B is read out.
    ZeroWeave_89601607729830_kernel<<<NPLANES, BLOCK, 0, stream>>>(x, out);
    ZeroWeave_89601607729830_kernel<<<NPLANES, BLOCK, 0, stream>>>(x, out);
    ZeroWeave_89601607729830_kernel<<<NPLANES, BLOCK, 0, stream>>>(x, out);
}

// Round 7
// 336.616 us; speedup vs baseline: 1.4900x; 1.3985x over previous
//
#include <hip/hip_runtime.h>

// ZeroWeave: x[B,C,64,64] -> out[B,C,190,190], out[:,:,::3,::3]=x, rest 0.
// B=32, C=64, s=3. out = 295.7 MB, x = 33.5 MB -> memory floor ~52 us @6.3 TB/s.
//
// Final structure (calibrated via 3x-launch A/Bs, R8-R10):
//   - dur_us = ~263 us harness overhead (poison fill ~190 + tiny restore
//     dispatches ~75) + kernel. Overhead model reproduces R4/R7/R8 exactly.
//   - Kernel ladder (calibrated): global-NT-read+store (R7/R9) = 79.7 us
//     (4.1 TB/s) regardless of sweep order / NT / instruction count;
//     LDS-staged store-PURE hot loop (R10) = ~65 us (~5.1 TB/s).
//     Mixing global reads into the store stream was the 15 us cost.
//   - Remaining gap to the 52 us floor (~13 us) = read/write turnaround +
//     DRAM row locality of 1KB/wave strided stores vs the fill's long runs;
//     below single-launch measurement noise. Practical roofline.
//
// Structure: 1 block/plane, BLOCK=320 (5 waves). Stage x plane (16 KB) into
// LDS with a coalesced float4 burst (all global reads up-front). Thread
// q<285 permanently owns pattern float4-slot q of the 6-row group (285
// float4 = 4560 B, 16B-aligned); its data/zero class and x offset are
// loop-invariant. g-loop writes one contiguous group per iteration in
// monotone address order -> every 128B line written exactly once, pure
// store stream (like the 6.37 TB/s rocclr fill). Zero slots compose via
// the same branchless cndmask path (LDS bank-0 broadcast dummy read).
//
// Pattern group: [0..47 data][48..141 zero][142..189 data][190..284 zero].
// Partial group g=31 = pattern slots 0..189 (rows 186..189).
// Verified data mapping (half: 0=pattern row 0, 1=row 3; x row = 2g+half):
//   c = rr/3, m = rr%3, cls = (m+half)%3, sel2 = half ? m==2 : m!=0,
//   xoff = half*64 + 4c + 2*sel2; compose {p0?vx, p2?vy, p1?vx, p0?vy}.

typedef float f32x4 __attribute__((ext_vector_type(4)));
typedef float f32x2 __attribute__((ext_vector_type(2)));

constexpr int NPLANES    = 32 * 64;   // 2048
constexpr int BLOCK      = 320;       // 5 waves; threads 0..284 own one slot
constexpr int PLANE_IN_F = 64 * 64;   // 4096 floats = 16 KB
constexpr int PLANE_OUT4 = 9025;      // 190*190/4 float4
constexpr int GROUP4     = 285;       // float4 per 6-row group
constexpr int GROUPS     = 31;        // full groups (rows 0..185)

__global__ __launch_bounds__(BLOCK) void ZeroWeave_89601607729830_kernel(
    const float* __restrict__ x, float* __restrict__ out) {
    __shared__ float xs[PLANE_IN_F];

    const int bc = blockIdx.x;
    const int t  = threadIdx.x;

    // ---- stage x plane -> LDS (coalesced float4; all reads up-front).
    {
        const f32x4* xp4 = reinterpret_cast<const f32x4*>(x + (size_t)bc * PLANE_IN_F);
        f32x4* xl = reinterpret_cast<f32x4*>(xs);
#pragma unroll
        for (int k = 0; k < 4; ++k) {
            const int i = k * BLOCK + t;
            if (i < PLANE_IN_F / 4) xl[i] = xp4[i];
        }
    }
    __syncthreads();
    if (t >= GROUP4) return;          // after the barrier!

    f32x4* op = reinterpret_cast<f32x4*>(out) + (size_t)bc * PLANE_OUT4;

    // ---- loop-invariant slot classification (pattern slot t).
    int  half   = 0;
    int  rr     = 0;
    bool isData = false;
    if (t < 48)                    { isData = true; half = 0; rr = t; }
    else if (t >= 142 && t < 190)  { isData = true; half = 1; rr = t - 142; }
    const unsigned c = (unsigned)rr / 3u;
    const unsigned m = (unsigned)rr - 3u * c;
    unsigned cls = m + (unsigned)half;
    if (cls >= 3u) cls -= 3u;
    const int  sel2 = half ? (m == 2u) : (m != 0u);
    const int  xoff = isData ? (half * 64 + 4 * (int)c + 2 * sel2) : 0;
    const bool p0 = isData && (cls == 0u);
    const bool p1 = isData && (cls == 1u);
    const bool p2 = isData && (cls == 2u);

    const float* xa = xs + xoff;   // + g*128 per group (zero threads: bank-0 bcast)
    f32x4* oa = op + t;            // + g*285 per group

    // ---- single sweep: one contiguous 4560B group per iteration, in order.
    // Hot-loop global traffic = stores ONLY (pure store stream, like the fill).
#pragma unroll 4
    for (int g = 0; g < GROUPS; ++g) {
        const f32x2 v = *reinterpret_cast<const f32x2*>(xa + g * 128);
        f32x4 o;
        o.x = p0 ? v.x : 0.0f;
        o.y = p2 ? v.y : 0.0f;
        o.z = p1 ? v.x : 0.0f;
        o.w = p0 ? v.y : 0.0f;
        oa[g * GROUP4] = o;
    }
    // ---- partial group g=31: rows 186..189 = pattern slots 0..189.
    if (t < 190) {
        const f32x2 v = *reinterpret_cast<const f32x2*>(xa + GROUPS * 128);
        f32x4 o;
        o.x = p0 ? v.x : 0.0f;
        o.y = p2 ? v.y : 0.0f;
        o.z = p1 ? v.x : 0.0f;
        o.w = p0 ? v.y : 0.0f;
        oa[GROUPS * GROUP4] = o;
    }
}

extern "C" void kernel_launch(void* const* d_in, const int* in_sizes, int n_in,
                              void* d_out, int out_size, void* d_ws, size_t ws_size,
                              hipStream_t stream) {
    const float* x = (const float*)d_in[0];
    // d_in[1] is num_zeros (==2), baked into constants.
    float* out = (float*)d_out;

    ZeroWeave_89601607729830_kernel<<<NPLANES, BLOCK, 0, stream>>>(x, out);
}